// Round 6
// baseline (12.821 us; speedup 1.0000x reference)
//
#include <hip/hip_runtime.h>
#include <math.h>

// LorentzRankingLoss, single-dispatch fused, dedicated-reducer-block version.
// Pair blocks (blockIdx 1..nb) each handle 256 (anchor,negative) pairs and
// publish their partial as (1<<32 | float_bits) into an atomic slot in d_ws.
// Block 0 is a pure reducer: its 256 threads spin-consume slots from t~0
// (overlapping all producer compute), wave+LDS reduce, write the mean.
// Slots self-reset to 0 -> deterministic and poison-proof across replays
// (0xAA poison and 0 both fail the flag==1 test).

#define NUM_NEG 8
#define BLK 256

__device__ __forceinline__ float lorentz_dist_row(const float x[32], float xt,
                                                  const float* __restrict__ yrow) {
    float yy0 = 0.f, yy1 = 0.f, yy2 = 0.f, yy3 = 0.f;
    float dt0 = 0.f, dt1 = 0.f, dt2 = 0.f, dt3 = 0.f;
#pragma unroll
    for (int q = 0; q < 8; ++q) {
        float4 y4 = reinterpret_cast<const float4*>(yrow)[q];
        yy0 = fmaf(y4.x, y4.x, yy0); dt0 = fmaf(y4.x, x[q * 4 + 0], dt0);
        yy1 = fmaf(y4.y, y4.y, yy1); dt1 = fmaf(y4.y, x[q * 4 + 1], dt1);
        yy2 = fmaf(y4.z, y4.z, yy2); dt2 = fmaf(y4.z, x[q * 4 + 2], dt2);
        yy3 = fmaf(y4.w, y4.w, yy3); dt3 = fmaf(y4.w, x[q * 4 + 3], dt3);
    }
    float yy  = (yy0 + yy1) + (yy2 + yy3);
    float dot = (dt0 + dt1) + (dt2 + dt3);
    float yt  = sqrtf(1.0f + yy);
    float arg = fmaxf(fmaf(xt, yt, -dot), 1.0f + 1e-7f);
    // acosh(arg) = log(arg + sqrt(arg^2-1)); branch-free, arg >= 1 guaranteed
    return __logf(arg + sqrtf(fmaf(arg, arg, -1.0f)));
}

__global__ __launch_bounds__(BLK)
void lorentz_fused_kernel(const float* __restrict__ voxel,   // [32][S]
                          const float* __restrict__ label,   // [C][32]
                          const int* __restrict__ sidx,      // [K]
                          const int* __restrict__ scls,      // [K]
                          const int* __restrict__ negc,      // [K][8]
                          unsigned long long* __restrict__ slots, // [nb]
                          float* __restrict__ out,
                          int K, int S, int nb, float scale) {
    int lane = threadIdx.x & 63, w = threadIdx.x >> 6;

    if (blockIdx.x == 0) {
        // ---- dedicated reducer: consume slots as they appear ----
        float s = 0.f;
        for (int i = threadIdx.x; i < nb; i += BLK) {      // <=1 slot/thread
            unsigned long long v;
            do {
                v = atomicExch(&slots[i], 0ULL);           // consume + reset
            } while ((v >> 32) != 1ULL);
            s += __uint_as_float((unsigned)(v & 0xffffffffULL));
        }
#pragma unroll
        for (int o = 32; o > 0; o >>= 1) s += __shfl_down(s, o);

        __shared__ float cs4[BLK / 64];
        if (lane == 0) cs4[w] = s;
        __syncthreads();
        if (threadIdx.x == 0)
            out[0] = ((cs4[0] + cs4[1]) + (cs4[2] + cs4[3])) * scale;
        return;
    }

    // ---- producer blocks: 256 (anchor,negative) pairs each ----
    int t = (blockIdx.x - 1) * BLK + threadIdx.x;
    float tri = 0.f;
    if (t < K * NUM_NEG) {
        int a = t >> 3;               // anchor; 8 sibling lanes share addresses
        int idx = sidx[a];
        float x[32];
#pragma unroll
        for (int d = 0; d < 32; ++d)
            x[d] = voxel[(size_t)d * (size_t)S + (size_t)idx];

        float x0 = 0.f, x1 = 0.f, x2 = 0.f, x3 = 0.f;
#pragma unroll
        for (int d = 0; d < 32; d += 4) {
            x0 = fmaf(x[d + 0], x[d + 0], x0);
            x1 = fmaf(x[d + 1], x[d + 1], x1);
            x2 = fmaf(x[d + 2], x[d + 2], x2);
            x3 = fmaf(x[d + 3], x[d + 3], x3);
        }
        float xt = sqrtf(1.0f + ((x0 + x1) + (x2 + x3)));

        float dpos = lorentz_dist_row(x, xt, label + (size_t)scls[a] * 32);
        float dneg = lorentz_dist_row(x, xt, label + (size_t)negc[t] * 32);
        tri = fmaxf(0.1f + dpos - dneg, 0.f);
    }

    // wave reduce (64 lanes), then cross-wave via LDS (4 waves)
#pragma unroll
    for (int o = 32; o > 0; o >>= 1) tri += __shfl_down(tri, o);

    __shared__ float ws4[BLK / 64];
    if (lane == 0) ws4[w] = tri;
    __syncthreads();

    if (threadIdx.x == 0) {
        float p = (ws4[0] + ws4[1]) + (ws4[2] + ws4[3]);
        unsigned long long payload =
            (1ULL << 32) | (unsigned long long)__float_as_uint(p);
        atomicExch(&slots[blockIdx.x - 1], payload);
    }
}

extern "C" void kernel_launch(void* const* d_in, const int* in_sizes, int n_in,
                              void* d_out, int out_size, void* d_ws, size_t ws_size,
                              hipStream_t stream) {
    const float* voxel = (const float*)d_in[0];   // [1,32,S]
    // d_in[1] = labels (unused)
    const float* label = (const float*)d_in[2];   // [105,32]
    const int* sidx    = (const int*)d_in[3];     // [K]
    const int* scls    = (const int*)d_in[4];     // [K]
    const int* negc    = (const int*)d_in[5];     // [K,8]

    int K = in_sizes[3];
    int S = in_sizes[1];                          // B*H*W*Z (B=1)

    unsigned long long* slots = (unsigned long long*)d_ws;
    float* out = (float*)d_out;

    int total = K * NUM_NEG;
    int nb = (total + BLK - 1) / BLK;             // 210 producer blocks
    lorentz_fused_kernel<<<nb + 1, BLK, 0, stream>>>(voxel, label, sidx, scls,
                                                     negc, slots, out, K, S, nb,
                                                     1.0f / (float)total);
}

// Round 7
// 11.479 us; speedup vs baseline: 1.1169x; 1.1169x over previous
//
#include <hip/hip_runtime.h>
#include <math.h>

// LorentzRankingLoss, single-dispatch fused — best-measured structure (R3):
// 210 x 256-thread blocks; every block computes 256 (anchor,negative) pairs,
// publishes its partial as (1<<32 | float_bits) into an atomic slot in d_ws;
// block 0's wave 0 then consumes all slots (spin-atomicExch to 0, 4/lane),
// reduces in fixed lane order, writes the mean. Slots self-reset to 0 ->
// deterministic and poison-proof across graph replays.
// Math: 4-way split fma chains + branch-free acosh via log identity (exact
// to ~1e-6, verified absmax 0.0 vs reference).

#define NUM_NEG 8
#define BLK 256

__device__ __forceinline__ float lorentz_dist_row(const float x[32], float xt,
                                                  const float* __restrict__ yrow) {
    float yy0 = 0.f, yy1 = 0.f, yy2 = 0.f, yy3 = 0.f;
    float dt0 = 0.f, dt1 = 0.f, dt2 = 0.f, dt3 = 0.f;
#pragma unroll
    for (int q = 0; q < 8; ++q) {
        float4 y4 = reinterpret_cast<const float4*>(yrow)[q];
        yy0 = fmaf(y4.x, y4.x, yy0); dt0 = fmaf(y4.x, x[q * 4 + 0], dt0);
        yy1 = fmaf(y4.y, y4.y, yy1); dt1 = fmaf(y4.y, x[q * 4 + 1], dt1);
        yy2 = fmaf(y4.z, y4.z, yy2); dt2 = fmaf(y4.z, x[q * 4 + 2], dt2);
        yy3 = fmaf(y4.w, y4.w, yy3); dt3 = fmaf(y4.w, x[q * 4 + 3], dt3);
    }
    float yy  = (yy0 + yy1) + (yy2 + yy3);
    float dot = (dt0 + dt1) + (dt2 + dt3);
    float yt  = sqrtf(1.0f + yy);
    float arg = fmaxf(fmaf(xt, yt, -dot), 1.0f + 1e-7f);
    // acosh(arg) = log(arg + sqrt(arg^2-1)); branch-free, arg >= 1 guaranteed
    return __logf(arg + sqrtf(fmaf(arg, arg, -1.0f)));
}

__global__ __launch_bounds__(BLK)
void lorentz_fused_kernel(const float* __restrict__ voxel,   // [32][S]
                          const float* __restrict__ label,   // [C][32]
                          const int* __restrict__ sidx,      // [K]
                          const int* __restrict__ scls,      // [K]
                          const int* __restrict__ negc,      // [K][8]
                          unsigned long long* __restrict__ slots, // [nb]
                          float* __restrict__ out,
                          int K, int S, int nb, float scale) {
    int t = blockIdx.x * BLK + threadIdx.x;
    float tri = 0.f;
    if (t < K * NUM_NEG) {
        int a = t >> 3;               // anchor; 8 sibling lanes share addresses
        int idx = sidx[a];
        float x[32];
#pragma unroll
        for (int d = 0; d < 32; ++d)
            x[d] = voxel[(size_t)d * (size_t)S + (size_t)idx];

        float x0 = 0.f, x1 = 0.f, x2 = 0.f, x3 = 0.f;
#pragma unroll
        for (int d = 0; d < 32; d += 4) {
            x0 = fmaf(x[d + 0], x[d + 0], x0);
            x1 = fmaf(x[d + 1], x[d + 1], x1);
            x2 = fmaf(x[d + 2], x[d + 2], x2);
            x3 = fmaf(x[d + 3], x[d + 3], x3);
        }
        float xt = sqrtf(1.0f + ((x0 + x1) + (x2 + x3)));

        float dpos = lorentz_dist_row(x, xt, label + (size_t)scls[a] * 32);
        float dneg = lorentz_dist_row(x, xt, label + (size_t)negc[t] * 32);
        tri = fmaxf(0.1f + dpos - dneg, 0.f);
    }

    // wave reduce (64 lanes), then cross-wave via LDS (4 waves)
#pragma unroll
    for (int o = 32; o > 0; o >>= 1) tri += __shfl_down(tri, o);

    __shared__ float ws4[BLK / 64];
    int lane = threadIdx.x & 63, w = threadIdx.x >> 6;
    if (lane == 0) ws4[w] = tri;
    __syncthreads();

    // publish this block's partial: flag(1) and value share one atomic word
    if (threadIdx.x == 0) {
        float p = (ws4[0] + ws4[1]) + (ws4[2] + ws4[3]);
        unsigned long long payload =
            (1ULL << 32) | (unsigned long long)__float_as_uint(p);
        atomicExch(&slots[blockIdx.x], payload);
    }

    // block 0, wave 0: consume all slots (parallel spin), fixed-order sum
    if (blockIdx.x == 0 && threadIdx.x < 64) {
        float s = 0.f;
        for (int i = threadIdx.x; i < nb; i += 64) {
            unsigned long long v;
            do {
                v = atomicExch(&slots[i], 0ULL);       // consume + reset
            } while ((v >> 32) != 1ULL);
            s += __uint_as_float((unsigned)(v & 0xffffffffULL));
        }
#pragma unroll
        for (int o = 32; o > 0; o >>= 1) s += __shfl_down(s, o);
        if (threadIdx.x == 0) out[0] = s * scale;
    }
}

extern "C" void kernel_launch(void* const* d_in, const int* in_sizes, int n_in,
                              void* d_out, int out_size, void* d_ws, size_t ws_size,
                              hipStream_t stream) {
    const float* voxel = (const float*)d_in[0];   // [1,32,S]
    // d_in[1] = labels (unused)
    const float* label = (const float*)d_in[2];   // [105,32]
    const int* sidx    = (const int*)d_in[3];     // [K]
    const int* scls    = (const int*)d_in[4];     // [K]
    const int* negc    = (const int*)d_in[5];     // [K,8]

    int K = in_sizes[3];
    int S = in_sizes[1];                          // B*H*W*Z (B=1)

    unsigned long long* slots = (unsigned long long*)d_ws;
    float* out = (float*)d_out;

    int total = K * NUM_NEG;
    int nb = (total + BLK - 1) / BLK;             // 210 blocks for K=6720
    lorentz_fused_kernel<<<nb, BLK, 0, stream>>>(voxel, label, sidx, scls, negc,
                                                 slots, out, K, S, nb,
                                                 1.0f / (float)total);
}